// Round 1
// baseline (176.545 us; speedup 1.0000x reference)
//
#include <hip/hip_runtime.h>

// RotarySelfAttention: B=1 T=4096 C=1024 NH=16 NKV=4 HD=64 WIN=1024
// Pipeline: f2b converts -> QKV GEMM (bf16 MFMA) -> RMSNorm+RoPE -> sliding-window
// GQA flash attention (bf16 MFMA) -> output GEMM -> fp32 out.

#define T_SEQ 4096
#define WIN_SZ 1024

typedef __attribute__((ext_vector_type(8))) short short8;
typedef __attribute__((ext_vector_type(8))) unsigned short ushort8;
typedef __attribute__((ext_vector_type(4))) float f32x4;

__device__ __forceinline__ unsigned short f2bf(float f) {
  union { float f; unsigned u; } v; v.f = f;
  unsigned r = v.u + 0x7fffu + ((v.u >> 16) & 1u);
  return (unsigned short)(r >> 16);
}

// ---------------- fp32 -> bf16 convert ----------------
__global__ __launch_bounds__(256) void k_f2b(const float* __restrict__ src,
                                             unsigned short* __restrict__ dst, int n) {
  int i = (blockIdx.x * 256 + threadIdx.x) * 4;
  if (i + 3 < n) {
    float4 v = *(const float4*)(src + i);
    dst[i + 0] = f2bf(v.x);
    dst[i + 1] = f2bf(v.y);
    dst[i + 2] = f2bf(v.z);
    dst[i + 3] = f2bf(v.w);
  }
}

// ---------------- bf16 GEMM: C[M][N] = A[M][K] * B[N][K]^T, fp32 out ----------------
// 128x128 tile, BK=64, 4 waves (2x2), each wave 64x64 via 4x4 mfma_16x16x32 frags.
// LDS rows are 128 B with XOR swizzle byte^=((row&7)<<4) (write and read use same map).
__global__ __launch_bounds__(256) void k_gemm_bt(const unsigned short* __restrict__ A,
                                                 const unsigned short* __restrict__ B,
                                                 float* __restrict__ C,
                                                 int M, int N, int K) {
  __shared__ unsigned short As[128 * 64];
  __shared__ unsigned short Bs[128 * 64];
  char* Asb = (char*)As;
  char* Bsb = (char*)Bs;
  const int tid = threadIdx.x;
  const int w = tid >> 6, l = tid & 63;
  const int wr = w >> 1, wc = w & 1;
  const int r = l & 15, g = l >> 4;
  const int m0 = blockIdx.y * 128, n0 = blockIdx.x * 128;
  const int crow = tid >> 3, cslot = tid & 7;

  f32x4 acc[4][4];
#pragma unroll
  for (int i = 0; i < 4; i++)
#pragma unroll
    for (int j = 0; j < 4; j++) acc[i][j] = {0.f, 0.f, 0.f, 0.f};

  for (int k0 = 0; k0 < K; k0 += 64) {
#pragma unroll
    for (int i = 0; i < 4; i++) {
      int row = crow + i * 32;
      int dst = row * 128 + ((cslot * 16) ^ ((row & 7) << 4));
      ushort8 va = *(const ushort8*)(A + (size_t)(m0 + row) * K + k0 + cslot * 8);
      *(ushort8*)(Asb + dst) = va;
      ushort8 vb = *(const ushort8*)(B + (size_t)(n0 + row) * K + k0 + cslot * 8);
      *(ushort8*)(Bsb + dst) = vb;
    }
    __syncthreads();
#pragma unroll
    for (int kk = 0; kk < 2; kk++) {
      short8 af[4], bfr[4];
#pragma unroll
      for (int mi = 0; mi < 4; mi++) {
        int row = wr * 64 + mi * 16 + r;
        af[mi] = *(const short8*)(Asb + row * 128 + ((kk * 64 + g * 16) ^ ((row & 7) << 4)));
      }
#pragma unroll
      for (int nj = 0; nj < 4; nj++) {
        int row = wc * 64 + nj * 16 + r;
        bfr[nj] = *(const short8*)(Bsb + row * 128 + ((kk * 64 + g * 16) ^ ((row & 7) << 4)));
      }
#pragma unroll
      for (int mi = 0; mi < 4; mi++)
#pragma unroll
        for (int nj = 0; nj < 4; nj++)
          acc[mi][nj] = __builtin_amdgcn_mfma_f32_16x16x32_bf16(af[mi], bfr[nj], acc[mi][nj], 0, 0, 0);
    }
    __syncthreads();
  }

#pragma unroll
  for (int mi = 0; mi < 4; mi++)
#pragma unroll
    for (int nj = 0; nj < 4; nj++) {
      int row = m0 + wr * 64 + mi * 16 + g * 4;
      int col = n0 + wc * 64 + nj * 16 + r;
#pragma unroll
      for (int e = 0; e < 4; e++)
        C[(size_t)(row + e) * N + col] = acc[mi][nj][e];
    }
}

// ---------------- RMSNorm + RoPE (+ V convert) ----------------
// wave per (t, unit): units 0-15 Q heads, 16-19 K heads, 20-23 V heads. lane = dim 0..63.
__global__ __launch_bounds__(256) void k_normrope(const float* __restrict__ QKV,
                                                  const float* __restrict__ qw,
                                                  const float* __restrict__ kw,
                                                  const float* __restrict__ fc,
                                                  const float* __restrict__ fs,
                                                  unsigned short* __restrict__ Qb,
                                                  unsigned short* __restrict__ Kb,
                                                  unsigned short* __restrict__ Vb) {
  int gid = blockIdx.x * 4 + (threadIdx.x >> 6);
  int l = threadIdx.x & 63;
  int t = gid / 24;
  int u = gid - t * 24;
  if (u < 16) {
    float v = QKV[(size_t)t * 1536 + u * 64 + l];
    float ss = v * v;
#pragma unroll
    for (int off = 32; off; off >>= 1) ss += __shfl_xor(ss, off);
    float rms = rsqrtf(ss * (1.0f / 64.0f) + 1e-5f);
    float vn = v * rms * qw[l];
    float c = fc[t * 32 + (l >> 1)], s = fs[t * 32 + (l >> 1)];
    float p = __shfl_xor(vn, 1);
    float out = (l & 1) ? (p * s + vn * c) : (vn * c - p * s);
    Qb[(size_t)t * 1024 + u * 64 + l] = f2bf(out);
  } else if (u < 20) {
    int hh = u - 16;
    float v = QKV[(size_t)t * 1536 + 1024 + hh * 64 + l];
    float ss = v * v;
#pragma unroll
    for (int off = 32; off; off >>= 1) ss += __shfl_xor(ss, off);
    float rms = rsqrtf(ss * (1.0f / 64.0f) + 1e-5f);
    float vn = v * rms * kw[l];
    float c = fc[t * 32 + (l >> 1)], s = fs[t * 32 + (l >> 1)];
    float p = __shfl_xor(vn, 1);
    float out = (l & 1) ? (p * s + vn * c) : (vn * c - p * s);
    Kb[(size_t)t * 256 + hh * 64 + l] = f2bf(out);
  } else {
    int hh = u - 20;
    Vb[(size_t)t * 256 + hh * 64 + l] = f2bf(QKV[(size_t)t * 1536 + 1280 + hh * 64 + l]);
  }
}

// ---------------- sliding-window GQA flash attention ----------------
// block: (q-tile of 64, head). 4 waves, wave w owns q rows [q0+16w, q0+16w+16).
// Per j-tile (64 keys): stage K swizzled + V transposed-swizzled in LDS, S = Q K^T via
// MFMA, online softmax in regs, P -> per-wave LDS, O += P V via MFMA.
__global__ __launch_bounds__(256) void k_attn(const unsigned short* __restrict__ Qb,
                                              const unsigned short* __restrict__ Kb,
                                              const unsigned short* __restrict__ Vb,
                                              unsigned short* __restrict__ Yb) {
  const int q0 = blockIdx.x * 64;
  const int h = blockIdx.y;
  const int hk = h >> 2;
  const int tid = threadIdx.x, w = tid >> 6, l = tid & 63;
  const int r = l & 15, g = l >> 4;
  __shared__ unsigned short Ks[64 * 64];
  __shared__ unsigned short Vts[64 * 64];
  __shared__ unsigned short Ps[4 * 16 * 64];
  char* Ksb = (char*)Ks;
  char* Vtsb = (char*)Vts;
  char* Psb = (char*)Ps;

  const int qrow = q0 + w * 16 + r;
  short8 aq[2];
#pragma unroll
  for (int kk = 0; kk < 2; kk++)
    aq[kk] = *(const short8*)(Qb + (size_t)qrow * 1024 + h * 64 + kk * 32 + g * 8);

  f32x4 accO[4];
#pragma unroll
  for (int i = 0; i < 4; i++) accO[i] = {0.f, 0.f, 0.f, 0.f};
  float m[4] = {-1e30f, -1e30f, -1e30f, -1e30f};
  float lsum[4] = {0.f, 0.f, 0.f, 0.f};

  int jlo = q0 - (WIN_SZ - 1);
  if (jlo < 0) jlo = 0;
  jlo &= ~63;
  const int srow = tid >> 3, sslot = tid & 7;

  for (int jt = jlo; jt <= q0; jt += 64) {
    __syncthreads();
#pragma unroll
    for (int i = 0; i < 2; i++) {
      int row = srow + i * 32;
      ushort8 kv = *(const ushort8*)(Kb + (size_t)(jt + row) * 256 + hk * 64 + sslot * 8);
      *(ushort8*)(Ksb + row * 128 + ((sslot * 16) ^ ((row & 7) << 4))) = kv;
      ushort8 vv = *(const ushort8*)(Vb + (size_t)(jt + row) * 256 + hk * 64 + sslot * 8);
#pragma unroll
      for (int e = 0; e < 8; e++) {
        int d = sslot * 8 + e;
        *(unsigned short*)(Vtsb + d * 128 + ((row * 2) ^ ((d & 7) << 4))) = vv[e];
      }
    }
    __syncthreads();

    // S = Q K^T
    f32x4 accS[4];
#pragma unroll
    for (int i = 0; i < 4; i++) accS[i] = {0.f, 0.f, 0.f, 0.f};
#pragma unroll
    for (int kk = 0; kk < 2; kk++) {
#pragma unroll
      for (int nj = 0; nj < 4; nj++) {
        int row = nj * 16 + r;
        short8 bk = *(const short8*)(Ksb + row * 128 + ((kk * 64 + g * 16) ^ ((row & 7) << 4)));
        accS[nj] = __builtin_amdgcn_mfma_f32_16x16x32_bf16(aq[kk], bk, accS[nj], 0, 0, 0);
      }
    }

    // mask + online softmax
    const int qbase = q0 + w * 16 + g * 4;
    float sv[4][4];
#pragma unroll
    for (int nj = 0; nj < 4; nj++)
#pragma unroll
      for (int rr = 0; rr < 4; rr++) {
        int q = qbase + rr, j = jt + nj * 16 + r;
        float x = accS[nj][rr] * 0.125f;
        sv[nj][rr] = ((j <= q) && (q - j < WIN_SZ)) ? x : -__builtin_inff();
      }
#pragma unroll
    for (int rr = 0; rr < 4; rr++) {
      float mx = fmaxf(fmaxf(sv[0][rr], sv[1][rr]), fmaxf(sv[2][rr], sv[3][rr]));
#pragma unroll
      for (int off = 8; off; off >>= 1) mx = fmaxf(mx, __shfl_xor(mx, off));
      float mnew = fmaxf(m[rr], mx);
      float alpha = __expf(m[rr] - mnew);
      float rsum = 0.f;
#pragma unroll
      for (int nj = 0; nj < 4; nj++) {
        float p = __expf(sv[nj][rr] - mnew);
        sv[nj][rr] = p;
        rsum += p;
      }
#pragma unroll
      for (int off = 8; off; off >>= 1) rsum += __shfl_xor(rsum, off);
      lsum[rr] = lsum[rr] * alpha + rsum;
      m[rr] = mnew;
#pragma unroll
      for (int nd = 0; nd < 4; nd++) accO[nd][rr] *= alpha;
    }

    // P -> per-wave LDS (bf16, swizzled)
#pragma unroll
    for (int nj = 0; nj < 4; nj++)
#pragma unroll
      for (int rr = 0; rr < 4; rr++) {
        int prow = g * 4 + rr;
        *(unsigned short*)(Psb + w * 2048 + prow * 128 +
                           (((nj * 16 + r) * 2) ^ ((prow & 7) << 4))) = f2bf(sv[nj][rr]);
      }

    // O += P V
#pragma unroll
    for (int kk = 0; kk < 2; kk++) {
      short8 pa = *(const short8*)(Psb + w * 2048 + r * 128 + ((kk * 64 + g * 16) ^ ((r & 7) << 4)));
#pragma unroll
      for (int nd = 0; nd < 4; nd++) {
        int drow = nd * 16 + r;
        short8 vbf = *(const short8*)(Vtsb + drow * 128 + ((kk * 64 + g * 16) ^ ((drow & 7) << 4)));
        accO[nd] = __builtin_amdgcn_mfma_f32_16x16x32_bf16(pa, vbf, accO[nd], 0, 0, 0);
      }
    }
  }

#pragma unroll
  for (int nd = 0; nd < 4; nd++)
#pragma unroll
    for (int rr = 0; rr < 4; rr++) {
      float o = accO[nd][rr] / lsum[rr];
      Yb[(size_t)(q0 + w * 16 + g * 4 + rr) * 1024 + h * 64 + nd * 16 + r] = f2bf(o);
    }
}

extern "C" void kernel_launch(void* const* d_in, const int* in_sizes, int n_in,
                              void* d_out, int out_size, void* d_ws, size_t ws_size,
                              hipStream_t stream) {
  const float* x = (const float*)d_in[0];
  const float* wq = (const float*)d_in[1];
  const float* wk = (const float*)d_in[2];
  const float* wv = (const float*)d_in[3];
  const float* wo = (const float*)d_in[4];
  const float* qw = (const float*)d_in[5];
  const float* kw = (const float*)d_in[6];
  const float* fc = (const float*)d_in[7];
  const float* fs = (const float*)d_in[8];
  float* out = (float*)d_out;

  char* p = (char*)d_ws;
  auto alloc = [&](size_t b) {
    char* q = p;
    p += (b + 255) & ~(size_t)255;
    return q;
  };
  unsigned short* xb = (unsigned short*)alloc((size_t)4096 * 1024 * 2);
  unsigned short* wqkvb = (unsigned short*)alloc((size_t)1536 * 1024 * 2);
  unsigned short* wob = (unsigned short*)alloc((size_t)1024 * 1024 * 2);
  float* QKV = (float*)alloc((size_t)4096 * 1536 * 4);
  unsigned short* Qb = (unsigned short*)alloc((size_t)4096 * 1024 * 2);
  unsigned short* Kb = (unsigned short*)alloc((size_t)4096 * 256 * 2);
  unsigned short* Vb = (unsigned short*)alloc((size_t)4096 * 256 * 2);
  unsigned short* Yb = (unsigned short*)alloc((size_t)4096 * 1024 * 2);

  k_f2b<<<4096, 256, 0, stream>>>(x, xb, 4096 * 1024);
  k_f2b<<<1024, 256, 0, stream>>>(wq, wqkvb, 1024 * 1024);
  k_f2b<<<256, 256, 0, stream>>>(wk, wqkvb + 1024 * 1024, 256 * 1024);
  k_f2b<<<256, 256, 0, stream>>>(wv, wqkvb + 1280 * 1024, 256 * 1024);
  k_f2b<<<1024, 256, 0, stream>>>(wo, wob, 1024 * 1024);

  k_gemm_bt<<<dim3(12, 32), 256, 0, stream>>>(xb, wqkvb, QKV, 4096, 1536, 1024);
  k_normrope<<<24576, 256, 0, stream>>>(QKV, qw, kw, fc, fs, Qb, Kb, Vb);
  k_attn<<<dim3(64, 16), 256, 0, stream>>>(Qb, Kb, Vb, Yb);
  k_gemm_bt<<<dim3(8, 32), 256, 0, stream>>>(Yb, wob, out, 4096, 1024, 1024);
}

// Round 3
// 144.131 us; speedup vs baseline: 1.2249x; 1.2249x over previous
//
#include <hip/hip_runtime.h>
#include <hip/hip_bf16.h>

// RotarySelfAttention: B=1 T=4096 C=1024 NH=16 NKV=4 HD=64 WIN=1024
// f2b -> QKV GEMM (bf16 MFMA) -> RMSNorm+RoPE (Q pre-scaled, V transposed) ->
// swapped-operand 32x32 MFMA sliding-window flash attention -> out GEMM.

#define WIN_SZ 1024

typedef __attribute__((ext_vector_type(8))) short short8;
typedef __attribute__((ext_vector_type(8))) unsigned short ushort8;
typedef __attribute__((ext_vector_type(4))) float f32x4;
typedef __attribute__((ext_vector_type(16))) float f32x16;

__device__ __forceinline__ unsigned short f2bf(float f) {
  union { float f; unsigned u; } v; v.f = f;
  unsigned r = v.u + 0x7fffu + ((v.u >> 16) & 1u);
  return (unsigned short)(r >> 16);
}

__device__ __forceinline__ unsigned pk2bf(float lo, float hi) {
  __hip_bfloat162 h = __float22bfloat162_rn(make_float2(lo, hi));
  union { __hip_bfloat162 h; unsigned u; } c; c.h = h; return c.u;
}

__device__ __forceinline__ short8 frag4(unsigned w0, unsigned w1, unsigned w2, unsigned w3) {
  union { unsigned u[4]; short8 s; } x;
  x.u[0] = w0; x.u[1] = w1; x.u[2] = w2; x.u[3] = w3; return x.s;
}

// ---------------- fp32 -> bf16 convert ----------------
__global__ __launch_bounds__(256) void k_f2b(const float* __restrict__ src,
                                             unsigned short* __restrict__ dst, int n) {
  int i = (blockIdx.x * 256 + threadIdx.x) * 4;
  if (i + 3 < n) {
    float4 v = *(const float4*)(src + i);
    dst[i + 0] = f2bf(v.x);
    dst[i + 1] = f2bf(v.y);
    dst[i + 2] = f2bf(v.z);
    dst[i + 3] = f2bf(v.w);
  }
}

// ---------------- bf16 GEMM: C[M][N] = A[M][K] * B[N][K]^T, fp32 out ----------------
__global__ __launch_bounds__(256) void k_gemm_bt(const unsigned short* __restrict__ A,
                                                 const unsigned short* __restrict__ B,
                                                 float* __restrict__ C,
                                                 int M, int N, int K) {
  __shared__ unsigned short As[128 * 64];
  __shared__ unsigned short Bs[128 * 64];
  char* Asb = (char*)As;
  char* Bsb = (char*)Bs;
  const int tid = threadIdx.x;
  const int w = tid >> 6, l = tid & 63;
  const int wr = w >> 1, wc = w & 1;
  const int r = l & 15, g = l >> 4;
  const int m0 = blockIdx.y * 128, n0 = blockIdx.x * 128;
  const int crow = tid >> 3, cslot = tid & 7;

  f32x4 acc[4][4];
#pragma unroll
  for (int i = 0; i < 4; i++)
#pragma unroll
    for (int j = 0; j < 4; j++) acc[i][j] = {0.f, 0.f, 0.f, 0.f};

  for (int k0 = 0; k0 < K; k0 += 64) {
#pragma unroll
    for (int i = 0; i < 4; i++) {
      int row = crow + i * 32;
      int dst = row * 128 + ((cslot * 16) ^ ((row & 7) << 4));
      ushort8 va = *(const ushort8*)(A + (size_t)(m0 + row) * K + k0 + cslot * 8);
      *(ushort8*)(Asb + dst) = va;
      ushort8 vb = *(const ushort8*)(B + (size_t)(n0 + row) * K + k0 + cslot * 8);
      *(ushort8*)(Bsb + dst) = vb;
    }
    __syncthreads();
#pragma unroll
    for (int kk = 0; kk < 2; kk++) {
      short8 af[4], bfr[4];
#pragma unroll
      for (int mi = 0; mi < 4; mi++) {
        int row = wr * 64 + mi * 16 + r;
        af[mi] = *(const short8*)(Asb + row * 128 + ((kk * 64 + g * 16) ^ ((row & 7) << 4)));
      }
#pragma unroll
      for (int nj = 0; nj < 4; nj++) {
        int row = wc * 64 + nj * 16 + r;
        bfr[nj] = *(const short8*)(Bsb + row * 128 + ((kk * 64 + g * 16) ^ ((row & 7) << 4)));
      }
#pragma unroll
      for (int mi = 0; mi < 4; mi++)
#pragma unroll
        for (int nj = 0; nj < 4; nj++)
          acc[mi][nj] = __builtin_amdgcn_mfma_f32_16x16x32_bf16(af[mi], bfr[nj], acc[mi][nj], 0, 0, 0);
    }
    __syncthreads();
  }

#pragma unroll
  for (int mi = 0; mi < 4; mi++)
#pragma unroll
    for (int nj = 0; nj < 4; nj++) {
      int row = m0 + wr * 64 + mi * 16 + g * 4;
      int col = n0 + wc * 64 + nj * 16 + r;
#pragma unroll
      for (int e = 0; e < 4; e++)
        C[(size_t)(row + e) * N + col] = acc[mi][nj][e];
    }
}

// ---------------- RMSNorm + RoPE ----------------
// Q pre-scaled by 0.125*log2(e) (exp2-domain softmax). V written transposed:
// Vtg[(hh*64+d)*4096 + t].
__global__ __launch_bounds__(256) void k_normrope(const float* __restrict__ QKV,
                                                  const float* __restrict__ qw,
                                                  const float* __restrict__ kw,
                                                  const float* __restrict__ fc,
                                                  const float* __restrict__ fs,
                                                  unsigned short* __restrict__ Qb,
                                                  unsigned short* __restrict__ Kb,
                                                  unsigned short* __restrict__ Vtg) {
  int gid = blockIdx.x * 4 + (threadIdx.x >> 6);
  int l = threadIdx.x & 63;
  int t = gid / 24;
  int u = gid - t * 24;
  if (u < 16) {
    float v = QKV[(size_t)t * 1536 + u * 64 + l];
    float ss = v * v;
#pragma unroll
    for (int off = 32; off; off >>= 1) ss += __shfl_xor(ss, off);
    float rms = rsqrtf(ss * (1.0f / 64.0f) + 1e-5f);
    float vn = v * rms * qw[l];
    float c = fc[t * 32 + (l >> 1)], s = fs[t * 32 + (l >> 1)];
    float p = __shfl_xor(vn, 1);
    float out = (l & 1) ? (p * s + vn * c) : (vn * c - p * s);
    Qb[(size_t)t * 1024 + u * 64 + l] = f2bf(out * 0.1803368801111204f);
  } else if (u < 20) {
    int hh = u - 16;
    float v = QKV[(size_t)t * 1536 + 1024 + hh * 64 + l];
    float ss = v * v;
#pragma unroll
    for (int off = 32; off; off >>= 1) ss += __shfl_xor(ss, off);
    float rms = rsqrtf(ss * (1.0f / 64.0f) + 1e-5f);
    float vn = v * rms * kw[l];
    float c = fc[t * 32 + (l >> 1)], s = fs[t * 32 + (l >> 1)];
    float p = __shfl_xor(vn, 1);
    float out = (l & 1) ? (p * s + vn * c) : (vn * c - p * s);
    Kb[(size_t)t * 256 + hh * 64 + l] = f2bf(out);
  } else {
    int hh = u - 20;
    Vtg[(size_t)(hh * 64 + l) * 4096 + t] = f2bf(QKV[(size_t)t * 1536 + 1280 + hh * 64 + l]);
  }
}

// ---------------- swapped-operand 32x32 sliding-window flash attention ----------------
// Block: 128 q-rows x 1 head, 4 waves (wave w: q rows qw..qw+31). Per 64-key tile:
// stage K [64j][64d] and Vt [64d][64j] in LDS ([32][256B] rows, xor (row&15)<<4),
// S^T = mfma(Kfrag, Qfrag) so lane pair (l, l+32) owns P-row q = l&31 (16 j each);
// softmax in-register; P^T B-frags assembled via __shfl_xor(.,32) half-exchange;
// O^T += mfma(Vtfrag, Pfrag).
__global__ __launch_bounds__(256) void k_attn2(const unsigned short* __restrict__ Qb,
                                               const unsigned short* __restrict__ Kb,
                                               const unsigned short* __restrict__ Vtg,
                                               unsigned short* __restrict__ Yb) {
  const int q0 = blockIdx.x * 128;
  const int h = blockIdx.y;
  const int hk = h >> 2;
  const int tid = threadIdx.x, w = tid >> 6, l = tid & 63;
  const int l31 = l & 31, hi = l >> 5, l15 = l & 15;
  __shared__ unsigned short Ks[64 * 64];
  __shared__ unsigned short Vts[64 * 64];
  char* Ksb = (char*)Ks;
  char* Vtsb = (char*)Vts;

  const int qw = q0 + w * 32;
  const int qrow = qw + l31;
  short8 qf[4];
#pragma unroll
  for (int ks = 0; ks < 4; ks++)
    qf[ks] = *(const short8*)(Qb + (size_t)qrow * 1024 + h * 64 + ks * 16 + hi * 8);

  f32x16 accO0, accO1;
#pragma unroll
  for (int i = 0; i < 16; i++) { accO0[i] = 0.f; accO1[i] = 0.f; }
  float m = -1e30f, lsum = 0.f;

  int jlo = q0 - (WIN_SZ - 1);
  if (jlo < 0) jlo = 0;
  jlo &= ~63;
  const int jhi = q0 + 64;
  const int srow = tid >> 2;
  const int sr31 = srow & 31, srhl = (srow >> 5) * 128, srx = (srow & 15) << 4;

  for (int jt = jlo; jt <= jhi; jt += 64) {
    __syncthreads();
#pragma unroll
    for (int i = 0; i < 2; i++) {
      int slot = (tid & 3) + i * 4;
      int dst = sr31 * 256 + ((srhl + slot * 16) ^ srx);
      ushort8 kv = *(const ushort8*)(Kb + (size_t)(jt + srow) * 256 + hk * 64 + slot * 8);
      *(ushort8*)(Ksb + dst) = kv;
      ushort8 vv = *(const ushort8*)(Vtg + (size_t)(hk * 64 + srow) * 4096 + jt + slot * 8);
      *(ushort8*)(Vtsb + dst) = vv;
    }
    __syncthreads();
    if (jt > qw + 31 || jt + 63 < qw - (WIN_SZ - 1)) continue;

    // S^T: two 32-j subtiles
    f32x16 st0, st1;
#pragma unroll
    for (int i = 0; i < 16; i++) { st0[i] = 0.f; st1[i] = 0.f; }
#pragma unroll
    for (int ks = 0; ks < 4; ks++) {
      int colb = ks * 32 + hi * 16;
      short8 kf0 = *(const short8*)(Ksb + l31 * 256 + ((0 + colb) ^ (l15 << 4)));
      st0 = __builtin_amdgcn_mfma_f32_32x32x16_bf16(kf0, qf[ks], st0, 0, 0, 0);
      short8 kf1 = *(const short8*)(Ksb + l31 * 256 + ((128 + colb) ^ (l15 << 4)));
      st1 = __builtin_amdgcn_mfma_f32_32x32x16_bf16(kf1, qf[ks], st1, 0, 0, 0);
    }

    // mask (j = jt + 32*jj + 4*hi + (rg&3) + 8*(rg>>2))
    const int jb = jt + hi * 4;
#pragma unroll
    for (int rg = 0; rg < 16; rg++) {
      int j0 = jb + (rg & 3) + 8 * (rg >> 2);
      st0[rg] = ((j0 <= qrow) && (qrow - j0 < WIN_SZ)) ? st0[rg] : -__builtin_inff();
      int j1 = j0 + 32;
      st1[rg] = ((j1 <= qrow) && (qrow - j1 < WIN_SZ)) ? st1[rg] : -__builtin_inff();
    }

    // online softmax (exp2 domain), defer-max THR=8
    float mx = st0[0];
#pragma unroll
    for (int rg = 1; rg < 16; rg++) mx = fmaxf(mx, st0[rg]);
#pragma unroll
    for (int rg = 0; rg < 16; rg++) mx = fmaxf(mx, st1[rg]);
    mx = fmaxf(mx, __shfl_xor(mx, 32));
    if (!__all(mx <= m + 8.0f)) {
      float mnew = fmaxf(m, mx);
      float alpha = exp2f(m - mnew);
#pragma unroll
      for (int rg = 0; rg < 16; rg++) { accO0[rg] *= alpha; accO1[rg] *= alpha; }
      lsum *= alpha;
      m = mnew;
    }
    float ps = 0.f;
#pragma unroll
    for (int rg = 0; rg < 16; rg++) { st0[rg] = exp2f(st0[rg] - m); ps += st0[rg]; }
#pragma unroll
    for (int rg = 0; rg < 16; rg++) { st1[rg] = exp2f(st1[rg] - m); ps += st1[rg]; }
    lsum += ps;

    // pack P -> bf16 dwords. Lane half hi owns j = (rg&3) + 8*(rg>>2) + 4*hi.
    // pd0[jj][b] = (j=8b+4hi, j=8b+1+4hi); pd1[jj][b] = (j=8b+2+4hi, j=8b+3+4hi).
    unsigned pd0[2][4], pd1[2][4];
#pragma unroll
    for (int b = 0; b < 4; b++) {
      pd0[0][b] = pk2bf(st0[4 * b], st0[4 * b + 1]);
      pd1[0][b] = pk2bf(st0[4 * b + 2], st0[4 * b + 3]);
      pd0[1][b] = pk2bf(st1[4 * b], st1[4 * b + 1]);
      pd1[1][b] = pk2bf(st1[4 * b + 2], st1[4 * b + 3]);
    }

    // PV: O^T += Vt * P^T. B-frag dwords for K-slice ks2 (16 j):
    //  w0: lo lanes j(16ks2+0,1)   hi lanes j(16ks2+8,9)
    //  w1: lo (2,3)   hi (10,11)
    //  w2: lo (4,5)   hi (12,13)
    //  w3: lo (6,7)   hi (14,15)
    // Own-half data + partner half via __shfl_xor(.,32).
#pragma unroll
    for (int jj = 0; jj < 2; jj++) {
#pragma unroll
      for (int ks2 = 0; ks2 < 2; ks2++) {
        unsigned a0 = pd0[jj][2 * ks2], a1 = pd0[jj][2 * ks2 + 1];
        unsigned b0 = pd1[jj][2 * ks2], b1 = pd1[jj][2 * ks2 + 1];
        unsigned a0x = __shfl_xor(a0, 32), a1x = __shfl_xor(a1, 32);
        unsigned b0x = __shfl_xor(b0, 32), b1x = __shfl_xor(b1, 32);
        unsigned w0 = hi ? a1x : a0;
        unsigned w1 = hi ? b1x : b0;
        unsigned w2 = hi ? a1 : a0x;
        unsigned w3 = hi ? b1 : b0x;
        short8 pf = frag4(w0, w1, w2, w3);
        int colb = jj * 64 + ks2 * 32 + hi * 16;
        short8 vf0 = *(const short8*)(Vtsb + l31 * 256 + ((0 + colb) ^ (l15 << 4)));
        accO0 = __builtin_amdgcn_mfma_f32_32x32x16_bf16(vf0, pf, accO0, 0, 0, 0);
        short8 vf1 = *(const short8*)(Vtsb + l31 * 256 + ((128 + colb) ^ (l15 << 4)));
        accO1 = __builtin_amdgcn_mfma_f32_32x32x16_bf16(vf1, pf, accO1, 0, 0, 0);
      }
    }
  }

  lsum += __shfl_xor(lsum, 32);
  float inv = 1.0f / lsum;
#pragma unroll
  for (int dd = 0; dd < 2; dd++) {
    const f32x16& a = dd ? accO1 : accO0;
#pragma unroll
    for (int b = 0; b < 4; b++) {
      union { unsigned u[2]; ushort4 v; } o;
      o.u[0] = pk2bf(a[4 * b] * inv, a[4 * b + 1] * inv);
      o.u[1] = pk2bf(a[4 * b + 2] * inv, a[4 * b + 3] * inv);
      *(ushort4*)(Yb + (size_t)qrow * 1024 + h * 64 + dd * 32 + b * 8 + hi * 4) = o.v;
    }
  }
}

extern "C" void kernel_launch(void* const* d_in, const int* in_sizes, int n_in,
                              void* d_out, int out_size, void* d_ws, size_t ws_size,
                              hipStream_t stream) {
  const float* x = (const float*)d_in[0];
  const float* wq = (const float*)d_in[1];
  const float* wk = (const float*)d_in[2];
  const float* wv = (const float*)d_in[3];
  const float* wo = (const float*)d_in[4];
  const float* qw = (const float*)d_in[5];
  const float* kw = (const float*)d_in[6];
  const float* fc = (const float*)d_in[7];
  const float* fs = (const float*)d_in[8];
  float* out = (float*)d_out;

  char* p = (char*)d_ws;
  auto alloc = [&](size_t b) {
    char* q = p;
    p += (b + 255) & ~(size_t)255;
    return q;
  };
  unsigned short* xb = (unsigned short*)alloc((size_t)4096 * 1024 * 2);
  unsigned short* wqkvb = (unsigned short*)alloc((size_t)1536 * 1024 * 2);
  unsigned short* wob = (unsigned short*)alloc((size_t)1024 * 1024 * 2);
  float* QKV = (float*)alloc((size_t)4096 * 1536 * 4);
  unsigned short* Qb = (unsigned short*)alloc((size_t)4096 * 1024 * 2);
  unsigned short* Kb = (unsigned short*)alloc((size_t)4096 * 256 * 2);
  unsigned short* Vtg = (unsigned short*)alloc((size_t)256 * 4096 * 2);
  unsigned short* Yb = (unsigned short*)alloc((size_t)4096 * 1024 * 2);

  k_f2b<<<4096, 256, 0, stream>>>(x, xb, 4096 * 1024);
  k_f2b<<<1024, 256, 0, stream>>>(wq, wqkvb, 1024 * 1024);
  k_f2b<<<256, 256, 0, stream>>>(wk, wqkvb + 1024 * 1024, 256 * 1024);
  k_f2b<<<256, 256, 0, stream>>>(wv, wqkvb + 1280 * 1024, 256 * 1024);
  k_f2b<<<1024, 256, 0, stream>>>(wo, wob, 1024 * 1024);

  k_gemm_bt<<<dim3(12, 32), 256, 0, stream>>>(xb, wqkvb, QKV, 4096, 1536, 1024);
  k_normrope<<<24576, 256, 0, stream>>>(QKV, qw, kw, fc, fs, Qb, Kb, Vtg);
  k_attn2<<<dim3(32, 16), 256, 0, stream>>>(Qb, Kb, Vtg, Yb);
  k_gemm_bt<<<dim3(8, 32), 256, 0, stream>>>(Yb, wob, out, 4096, 1024, 1024);
}